// Round 1
// 285.938 us; speedup vs baseline: 1.0537x; 1.0537x over previous
//
#include <hip/hip_runtime.h>

// Caps layer: B=256 batches, S=512 input caps, D=256 in-dim, NC=16, DC=32, O=512.
// One block per batch, 512 threads (8 waves); grid 256 = 1 block/CU (structural).
// Factorized routing (u_hat never materialized):
//   y[n][D]   = sum_s c[n][s] x[s][D]
//   outputs   = squash_d( y[n] . W[:, n*32+d] )
//   z[n][D]   = sum_d W[D][n*32+d] outputs[n][d]
//   b[n][s]   = sum_D x[s][D] z[n][D]           (MFMA 16x16x32 bf16, fp32 acc)
//
// R1 change: FUSED routing pass. Old structure streamed x 5x per batch
// (rowsum, b-upd0, y1, b-upd1, y2) as separate barrier-split phases at
// ~4 TB/s effective => pass-count bound (HBM 25%, VALU 19%, Mfma 0.5%).
// New: per 16-s subtile, one wave does {MFMA b-tile -> in-reg softmax over n
// (2 shfl_xor across l4) -> 1KB c-tile to wave-private LDS -> f32 y-VALU
// re-reading the L1/L2-hot x tile}. x passes 5 -> 3; block-wide softmax
// phase + 3 barriers per iter deleted. y math bit-identical to old kernel
// (f32 c x f32 x, same order) => absmax unchanged.

#define S_ 512
#define D_ 256
#define O_ 512

typedef __attribute__((ext_vector_type(8))) short short8;
typedef __attribute__((ext_vector_type(4))) float floatx4;

__device__ __forceinline__ unsigned short f2b(float f) {
  union { float ff; unsigned int i; } v; v.ff = f;
  unsigned int u = v.i;
  return (unsigned short)((u + 0x7FFFu + ((u >> 16) & 1u)) >> 16);
}

__global__ __launch_bounds__(512, 2) void caps_kernel(
    const float* __restrict__ x, const float* __restrict__ W,
    float* __restrict__ out)
{
  // LDS (35328 B):
  //   ytmp f32 16x260 = 16640 B: y[n][D]
  //   zb   u16 16x264 =  8448 B: z bf16 (528 B rows, MFMA A-frag source)
  //   outp f32 512    =  2048 B
  //   cbuf f32 8x256  =  8192 B: per-wave c-tile [16n][16s]; iter-0 rowsum strips
  __shared__ __align__(16) float ytmp[16 * 260];
  __shared__ __align__(16) unsigned short zb[16 * 264];
  __shared__ __align__(16) float outp[O_];
  __shared__ __align__(16) float cbuf[8 * 256];

  const int tid  = threadIdx.x;
  const int wave = tid >> 6;
  const int lane = tid & 63;
  const int l15  = lane & 15;
  const int l4   = lane >> 4;
  const float* xb = x + (size_t)blockIdx.x * (S_ * D_);

  for (int it = 0; it < 3; ++it) {
    if (it == 0) {
      // ---- iter 0: b=0 -> c=1/16 uniform -> y[n][:] = (1/16)*rowsum(x) ----
      float a0 = 0.f, a1 = 0.f, a2 = 0.f, a3 = 0.f;
      #pragma unroll 4
      for (int r = 0; r < 64; ++r) {
        const int s = (wave << 6) + r;
        const float4 xv = *(const float4*)(xb + s * D_ + (lane << 2));
        a0 += xv.x; a1 += xv.y; a2 += xv.z; a3 += xv.w;
      }
      *(float4*)(cbuf + (wave << 8) + (lane << 2)) = make_float4(a0, a1, a2, a3);
      __syncthreads();
      if (tid < 256) {
        float v = 0.f;
        #pragma unroll
        for (int w = 0; w < 8; ++w) v += cbuf[(w << 8) + tid];
        v *= 0.0625f;
        #pragma unroll
        for (int n = 0; n < 16; ++n) ytmp[n * 260 + tid] = v;
      }
      __syncthreads();
    } else {
      // ---- FUSED pass: per 16-s subtile: b-tile MFMA -> softmax -> y-acc ----
      float acc[16][4];
      #pragma unroll
      for (int n = 0; n < 16; ++n) { acc[n][0]=0.f; acc[n][1]=0.f; acc[n][2]=0.f; acc[n][3]=0.f; }
      float* cw = cbuf + (wave << 8);   // wave-private c-tile [16n][16s]

      #pragma unroll 1
      for (int t = 0; t < 4; ++t) {
        const int s0 = (wave << 6) + (t << 4);
        // b-tile: b[16n x 16s] = z[16x256] * x^T[256x16]; fp32 acc
        floatx4 C = {0.f, 0.f, 0.f, 0.f};
        #pragma unroll
        for (int k = 0; k < 8; ++k) {
          // A-frag: z[m=l15][k*32 + l4*8 + j] from LDS (528 B rows, 16B-aligned)
          const short8 A = *(const short8*)(zb + l15 * 264 + (k << 5) + (l4 << 3));
          // B-frag: x[s0+l15][k*32 + l4*8 + j] fp32 global -> bf16
          const float* xp = xb + (s0 + l15) * D_ + (k << 5) + (l4 << 3);
          const float4 xv0 = *(const float4*)xp;
          const float4 xv1 = *(const float4*)(xp + 4);
          short8 Bf;
          Bf[0] = (short)f2b(xv0.x); Bf[1] = (short)f2b(xv0.y);
          Bf[2] = (short)f2b(xv0.z); Bf[3] = (short)f2b(xv0.w);
          Bf[4] = (short)f2b(xv1.x); Bf[5] = (short)f2b(xv1.y);
          Bf[6] = (short)f2b(xv1.z); Bf[7] = (short)f2b(xv1.w);
          C = __builtin_amdgcn_mfma_f32_16x16x32_bf16(A, Bf, C, 0, 0, 0);
        }
        // C/D layout: col = l15 (s), row = l4*4 + rg (n).
        // softmax over n: 4 regs local + reduce across l4 (lanes ^16, ^32)
        float m = fmaxf(fmaxf(C[0], C[1]), fmaxf(C[2], C[3]));
        m = fmaxf(m, __shfl_xor(m, 16, 64));
        m = fmaxf(m, __shfl_xor(m, 32, 64));
        const float e0 = __expf(C[0] - m), e1 = __expf(C[1] - m);
        const float e2 = __expf(C[2] - m), e3 = __expf(C[3] - m);
        float sm = e0 + e1 + e2 + e3;
        sm += __shfl_xor(sm, 16, 64);
        sm += __shfl_xor(sm, 32, 64);
        const float inv = 1.f / sm;
        const int nb = l4 << 2;
        cw[(nb + 0) * 16 + l15] = e0 * inv;   // 2-way bank alias only: free
        cw[(nb + 1) * 16 + l15] = e1 * inv;
        cw[(nb + 2) * 16 + l15] = e2 * inv;
        cw[(nb + 3) * 16 + l15] = e3 * inv;
        // same-wave LDS RAW: drain writes; "memory" clobber pins ordering
        asm volatile("s_waitcnt lgkmcnt(0)" ::: "memory");
        // y-acc: lane owns D-quad; x tile re-read is L1/L2-hot (just fetched)
        for (int g = 0; g < 4; ++g) {
          float cc[16][4];
          #pragma unroll
          for (int n = 0; n < 16; ++n) {
            const float4 c4 = *(const float4*)(cw + n * 16 + (g << 2));  // wave-uniform b128
            cc[n][0] = c4.x; cc[n][1] = c4.y; cc[n][2] = c4.z; cc[n][3] = c4.w;
          }
          #pragma unroll
          for (int j = 0; j < 4; ++j) {
            const float4 xv = *(const float4*)(xb + (s0 + (g << 2) + j) * D_ + (lane << 2));
            #pragma unroll
            for (int n = 0; n < 16; ++n) {
              acc[n][0] += cc[n][j] * xv.x; acc[n][1] += cc[n][j] * xv.y;
              acc[n][2] += cc[n][j] * xv.z; acc[n][3] += cc[n][j] * xv.w;
            }
          }
        }
      }
      // octant reduction into ytmp (8 serialized rounds; ~1-2 us total)
      for (int rr = 0; rr < 8; ++rr) {
        if (wave == rr) {
          #pragma unroll
          for (int n = 0; n < 16; ++n) {
            float4* p = (float4*)(ytmp + n * 260 + (lane << 2));
            if (rr == 0) { *p = make_float4(acc[n][0], acc[n][1], acc[n][2], acc[n][3]); }
            else { float4 v = *p; v.x += acc[n][0]; v.y += acc[n][1]; v.z += acc[n][2]; v.w += acc[n][3]; *p = v; }
          }
        }
        __syncthreads();
      }
    }

    // ---- outputs[n][d] = sum_D y[n][D] * W[D][n*32+d], then squash over d ----
    {
      const int o = tid;
      const int n = o >> 5;
      float a = 0.f;
      for (int Db = 0; Db < 32; ++Db) {
        const float4 y0 = *(const float4*)(ytmp + n * 260 + (Db << 3));
        const float4 y1 = *(const float4*)(ytmp + n * 260 + (Db << 3) + 4);
        const float* wp = W + (size_t)(Db << 3) * O_ + o;   // coalesced over o
        a += y0.x * wp[0 * O_]; a += y0.y * wp[1 * O_];
        a += y0.z * wp[2 * O_]; a += y0.w * wp[3 * O_];
        a += y1.x * wp[4 * O_]; a += y1.y * wp[5 * O_];
        a += y1.z * wp[6 * O_]; a += y1.w * wp[7 * O_];
      }
      float ss = a * a;
      #pragma unroll
      for (int off = 1; off < 32; off <<= 1) ss += __shfl_xor(ss, off, 64);
      const float v = a / sqrtf(ss + 1e-7f);
      outp[o] = v;
      if (it == 2) out[(size_t)blockIdx.x * O_ + o] = v;
    }
    __syncthreads();

    if (it < 2) {
      // ---- z[n][D] = sum_d W[D][n*32+d] * outputs[n][d]; wave owns 32 D-rows ----
      {
        const int obase = lane << 3;
        const int n_ln  = lane >> 2;
        float ov[8];
        #pragma unroll
        for (int j = 0; j < 8; ++j) ov[j] = outp[obase + j];
        for (int r = 0; r < 32; ++r) {
          const int Dd = (wave << 5) + r;
          const float4 w0 = *(const float4*)(W + (size_t)Dd * O_ + obase);
          const float4 w1 = *(const float4*)(W + (size_t)Dd * O_ + obase + 4);
          float a = w0.x * ov[0] + w0.y * ov[1] + w0.z * ov[2] + w0.w * ov[3]
                  + w1.x * ov[4] + w1.y * ov[5] + w1.z * ov[6] + w1.w * ov[7];
          a += __shfl_xor(a, 1, 64);
          a += __shfl_xor(a, 2, 64);
          if ((lane & 3) == 0) zb[n_ln * 264 + Dd] = f2b(a);
        }
      }
      __syncthreads();
    }
  }
}

extern "C" void kernel_launch(void* const* d_in, const int* in_sizes, int n_in,
                              void* d_out, int out_size, void* d_ws, size_t ws_size,
                              hipStream_t stream) {
  const float* x = (const float*)d_in[0];   // [256, 512, 256] f32
  const float* W = (const float*)d_in[1];   // [256, 512] f32
  float* out = (float*)d_out;               // [256*512] f32
  (void)in_sizes; (void)n_in; (void)out_size; (void)d_ws; (void)ws_size;
  caps_kernel<<<256, 512, 0, stream>>>(x, W, out);
}